// Round 5
// baseline (469.754 us; speedup 1.0000x reference)
//
#include <hip/hip_runtime.h>
#include <math.h>

// Problem constants (also derived at runtime from in_sizes)
// N0 = 200000 nodes, E0 = 1000000 edges, feat0 dim 62, RBF dim 64
// GAT1: 64 -> [2 heads x 8] = 16, GAT2: 16 -> [1 head x 64]
// Only the g_list[0] branch is live; g_list[1] branch is dead code wrt output.

#define LRELU(v) ((v) > 0.0f ? (v) : 0.2f * (v))

// ---------------------------------------------------------------------------
// Precompute wl[i] = sum_f W2[i,f]*al2[f], wr[i] = sum_f W2[i,f]*ar2[f]
// (so el2/er2 can be computed from h0 without materializing h0@W2)
// ---------------------------------------------------------------------------
__global__ __launch_bounds__(64) void k_prep(const float* __restrict__ W2,
                                             const float* __restrict__ al2,
                                             const float* __restrict__ ar2,
                                             float* __restrict__ wl,
                                             float* __restrict__ wr) {
    int i = threadIdx.x;
    if (i >= 16) return;
    float sl = 0.f, sr = 0.f;
    for (int f = 0; f < 64; ++f) {
        float w = W2[i * 64 + f];
        sl += w * al2[f];
        sr += w * ar2[f];
    }
    wl[i] = sl;
    wr[i] = sr;
}

// ---------------------------------------------------------------------------
// Fused: nf = sqrt(2/64)*cos(feat0 @ W_rbf0 + b_rbf0)  (kept in registers)
//        h1p = nf @ W1  [N,16];  el1[n,h] = sum_f h1p*al1; er1 likewise
// ---------------------------------------------------------------------------
__global__ __launch_bounds__(256) void k_rbf_proj(
    const float* __restrict__ feat0, const float* __restrict__ Wr,
    const float* __restrict__ br, const float* __restrict__ W1,
    const float* __restrict__ al1, const float* __restrict__ ar1,
    float* __restrict__ h1p, float* __restrict__ el1, float* __restrict__ er1,
    int N) {
    int n = blockIdx.x * blockDim.x + threadIdx.x;
    if (n >= N) return;

    float x[62];
    const float2* fp = reinterpret_cast<const float2*>(feat0 + (size_t)n * 62);
#pragma unroll
    for (int k = 0; k < 31; ++k) {
        float2 v = fp[k];
        x[2 * k] = v.x;
        x[2 * k + 1] = v.y;
    }

    float hp[16];
#pragma unroll
    for (int i = 0; i < 16; ++i) hp[i] = 0.f;

    const float cst = 0.17677669529663687f;  // sqrt(2/64)
#pragma unroll 4
    for (int j = 0; j < 64; ++j) {
        float acc = br[j];
#pragma unroll
        for (int k = 0; k < 62; ++k) acc += x[k] * Wr[k * 64 + j];
        float nfj = cst * cosf(acc);
#pragma unroll
        for (int i = 0; i < 16; ++i) hp[i] += nfj * W1[j * 16 + i];
    }

    float e_l[2] = {0.f, 0.f}, e_r[2] = {0.f, 0.f};
#pragma unroll
    for (int i = 0; i < 16; ++i) {
        e_l[i >> 3] += hp[i] * al1[i];
        e_r[i >> 3] += hp[i] * ar1[i];
    }

    float4* ho = reinterpret_cast<float4*>(h1p + (size_t)n * 16);
    ho[0] = make_float4(hp[0], hp[1], hp[2], hp[3]);
    ho[1] = make_float4(hp[4], hp[5], hp[6], hp[7]);
    ho[2] = make_float4(hp[8], hp[9], hp[10], hp[11]);
    ho[3] = make_float4(hp[12], hp[13], hp[14], hp[15]);
    el1[n * 2 + 0] = e_l[0];
    el1[n * 2 + 1] = e_l[1];
    er1[n * 2 + 0] = e_r[0];
    er1[n * 2 + 1] = e_r[1];
}

// ---------------------------------------------------------------------------
// Edge pass, GAT layer 1 (H=2, F=8). 16 lanes per edge: lane t = h*8+f.
// a = exp(leaky(el[src,h]+er[dst,h])); num[dst,t] += a*h1p[src,t]
// Softmax max-subtraction elided (shift-invariant; logits are O(0.1)).
// ---------------------------------------------------------------------------
__global__ __launch_bounds__(256) void k_edge1(
    const int* __restrict__ src, const int* __restrict__ dst,
    const float* __restrict__ el, const float* __restrict__ er,
    const float* __restrict__ hsrc, float* __restrict__ num,
    float* __restrict__ den, int E) {
    int tid = blockIdx.x * blockDim.x + threadIdx.x;
    int e = tid >> 4;
    if (e >= E) return;
    int t = tid & 15;
    int h = t >> 3;
    int s = src[e], d = dst[e];
    float v = el[s * 2 + h] + er[d * 2 + h];
    v = LRELU(v);
    float a = __expf(v);
    float hv = hsrc[(size_t)s * 16 + t];
    atomicAdd(&num[(size_t)d * 16 + t], a * hv);
    if ((t & 7) == 0) atomicAdd(&den[d * 2 + h], a);
}

// ---------------------------------------------------------------------------
// Finalize GAT1: h0 = relu(num/max(den,1e-9) + b1); el2 = h0.wl; er2 = h0.wr
// ---------------------------------------------------------------------------
__global__ __launch_bounds__(256) void k_fin1(
    const float* __restrict__ num, const float* __restrict__ den,
    const float* __restrict__ b1, const float* __restrict__ wl,
    const float* __restrict__ wr, float* __restrict__ h0,
    float* __restrict__ el2, float* __restrict__ er2, int N) {
    int n = blockIdx.x * blockDim.x + threadIdx.x;
    if (n >= N) return;
    float dn0 = fmaxf(den[n * 2 + 0], 1e-9f);
    float dn1 = fmaxf(den[n * 2 + 1], 1e-9f);
    const float4* np = reinterpret_cast<const float4*>(num + (size_t)n * 16);
    float q[16];
#pragma unroll
    for (int v4 = 0; v4 < 4; ++v4) {
        float4 nv = np[v4];
        q[v4 * 4 + 0] = nv.x;
        q[v4 * 4 + 1] = nv.y;
        q[v4 * 4 + 2] = nv.z;
        q[v4 * 4 + 3] = nv.w;
    }
    float sl = 0.f, sr = 0.f;
#pragma unroll
    for (int i = 0; i < 16; ++i) {
        float dn = (i < 8) ? dn0 : dn1;
        float val = q[i] / dn + b1[i];
        val = fmaxf(val, 0.f);
        q[i] = val;
        sl += val * wl[i];
        sr += val * wr[i];
    }
    float4* ho = reinterpret_cast<float4*>(h0 + (size_t)n * 16);
    ho[0] = make_float4(q[0], q[1], q[2], q[3]);
    ho[1] = make_float4(q[4], q[5], q[6], q[7]);
    ho[2] = make_float4(q[8], q[9], q[10], q[11]);
    ho[3] = make_float4(q[12], q[13], q[14], q[15]);
    el2[n] = sl;
    er2[n] = sr;
}

// ---------------------------------------------------------------------------
// Edge pass, GAT layer 2 (H=1). Projection deferred: scatter a*h0[src] (16 f).
// ---------------------------------------------------------------------------
__global__ __launch_bounds__(256) void k_edge2(
    const int* __restrict__ src, const int* __restrict__ dst,
    const float* __restrict__ el, const float* __restrict__ er,
    const float* __restrict__ h0, float* __restrict__ num,
    float* __restrict__ den, int E) {
    int tid = blockIdx.x * blockDim.x + threadIdx.x;
    int e = tid >> 4;
    if (e >= E) return;
    int t = tid & 15;
    int s = src[e], d = dst[e];
    float v = el[s] + er[d];
    v = LRELU(v);
    float a = __expf(v);
    float hv = h0[(size_t)s * 16 + t];
    atomicAdd(&num[(size_t)d * 16 + t], a * hv);
    if (t == 0) atomicAdd(&den[d], a);
}

// ---------------------------------------------------------------------------
// Sum over nodes of num2[n,:]/max(den2[n],1e-9)  -> s16[16]
// ---------------------------------------------------------------------------
__global__ __launch_bounds__(256) void k_sum(const float* __restrict__ num,
                                             const float* __restrict__ den,
                                             float* __restrict__ s16, int N) {
    int tid = blockIdx.x * blockDim.x + threadIdx.x;
    int t = tid & 15;
    int g = tid >> 4;
    int ngrp = (gridDim.x * blockDim.x) >> 4;
    float acc = 0.f;
    for (int n = g; n < N; n += ngrp) {
        float dn = fmaxf(den[n], 1e-9f);
        acc += num[(size_t)n * 16 + t] / dn;
    }
    __shared__ float lds[256];
    lds[threadIdx.x] = acc;
    __syncthreads();
    if (threadIdx.x < 16) {
        float s = 0.f;
        for (int i = threadIdx.x; i < 256; i += 16) s += lds[i];
        atomicAdd(&s16[threadIdx.x], s);
    }
}

// ---------------------------------------------------------------------------
// Tail: mean -> @W2 + b2 -> relu -> fc1 -> relu -> out  (tiny, 1 thread)
// ---------------------------------------------------------------------------
__global__ __launch_bounds__(64) void k_tail(
    const float* __restrict__ s16, const float* __restrict__ W2,
    const float* __restrict__ b2, const float* __restrict__ fc1w,
    const float* __restrict__ fc1b, const float* __restrict__ outw,
    const float* __restrict__ outb, float* __restrict__ out, float invN) {
    if (threadIdx.x != 0 || blockIdx.x != 0) return;
    float m[16];
#pragma unroll
    for (int i = 0; i < 16; ++i) m[i] = s16[i] * invN;
    float h16[16];
#pragma unroll
    for (int j = 0; j < 16; ++j) h16[j] = 0.f;
    for (int f = 0; f < 64; ++f) {
        float v = b2[f];
#pragma unroll
        for (int i = 0; i < 16; ++i) v += m[i] * W2[i * 64 + f];
        v = fmaxf(v, 0.f);  // relu(mean(out2))
#pragma unroll
        for (int j = 0; j < 16; ++j) h16[j] += v * fc1w[j * 64 + f];
    }
    float o = outb[0];
#pragma unroll
    for (int j = 0; j < 16; ++j) {
        float t = fmaxf(h16[j] + fc1b[j], 0.f);
        o += t * outw[j];
    }
    out[0] = o;
}

extern "C" void kernel_launch(void* const* d_in, const int* in_sizes, int n_in,
                              void* d_out, int out_size, void* d_ws,
                              size_t ws_size, hipStream_t stream) {
    // Input indices per setup_inputs() order
    const float* feat0 = (const float*)d_in[3];
    const int* src0 = (const int*)d_in[4];
    const int* dst0 = (const int*)d_in[5];
    const float* Wr = (const float*)d_in[9];
    const float* br = (const float*)d_in[10];
    const float* W1 = (const float*)d_in[19];   // g2c1_W [64,16]
    const float* al1 = (const float*)d_in[20];  // [2,8]
    const float* ar1 = (const float*)d_in[21];
    const float* b1 = (const float*)d_in[22];
    const float* W2 = (const float*)d_in[23];   // g2c2_W [16,64]
    const float* al2 = (const float*)d_in[24];  // [1,64]
    const float* ar2 = (const float*)d_in[25];
    const float* b2 = (const float*)d_in[26];
    const float* fc1w = (const float*)d_in[27];
    const float* fc1b = (const float*)d_in[28];
    const float* outw = (const float*)d_in[29];
    const float* outb = (const float*)d_in[30];

    const int N = in_sizes[3] / 62;
    const int E = in_sizes[4];
    const size_t Nz = (size_t)N;

    float* ws = (float*)d_ws;
    // zeroed region: [num1 16N][den1 2N][num2 16N][den2 N][s16 16]
    float* num1 = ws;
    float* den1 = ws + 16 * Nz;
    float* num2 = ws + 18 * Nz;
    float* den2 = ws + 34 * Nz;
    float* s16 = ws + 35 * Nz;
    // non-zeroed region
    float* wl = ws + 35 * Nz + 16;
    float* wr = ws + 35 * Nz + 32;
    float* h1p = ws + 35 * Nz + 48;
    float* el1 = h1p + 16 * Nz;
    float* er1 = el1 + 2 * Nz;
    float* h0 = er1 + 2 * Nz;
    float* el2 = h0 + 16 * Nz;
    float* er2 = el2 + Nz;

    hipMemsetAsync(ws, 0, (35 * Nz + 16) * sizeof(float), stream);

    const int nb = (N + 255) / 256;
    const long long etot = (long long)E * 16;
    const int eb = (int)((etot + 255) / 256);

    k_prep<<<1, 64, 0, stream>>>(W2, al2, ar2, wl, wr);
    k_rbf_proj<<<nb, 256, 0, stream>>>(feat0, Wr, br, W1, al1, ar1, h1p, el1,
                                       er1, N);
    k_edge1<<<eb, 256, 0, stream>>>(src0, dst0, el1, er1, h1p, num1, den1, E);
    k_fin1<<<nb, 256, 0, stream>>>(num1, den1, b1, wl, wr, h0, el2, er2, N);
    k_edge2<<<eb, 256, 0, stream>>>(src0, dst0, el2, er2, h0, num2, den2, E);
    k_sum<<<256, 256, 0, stream>>>(num2, den2, s16, N);
    k_tail<<<1, 64, 0, stream>>>(s16, W2, b2, fc1w, fc1b, outw, outb,
                                 (float*)d_out, 1.0f / (float)N);
}